// Round 1
// baseline (258.285 us; speedup 1.0000x reference)
//
#include <hip/hip_runtime.h>

#define NGRID 4194304
#define NCOEF (NGRID + 3)

// Cubic B-spline basis, replicating the reference's op structure:
// t<=1: 4 - 6t^2 + 3t^3 ; 1<t<=2: (2-t)^3 ; else 0
__device__ __forceinline__ float u_basis(float t) {
    t = fabsf(t);
    float tt = t * t;
    float inner = 4.0f - 6.0f * tt + 3.0f * tt * t;
    float om = 2.0f - t;
    float outer = om * om * om;
    float w = (t <= 1.0f) ? inner : outer;
    return (t <= 2.0f) ? w : 0.0f;
}

__global__ __launch_bounds__(256) void spline_eval_kernel(
    const float* __restrict__ x, const float* __restrict__ c,
    float* __restrict__ out, int n4)
{
    int tid = blockIdx.x * blockDim.x + threadIdx.x;
    int stride = gridDim.x * blockDim.x;
    const float4* __restrict__ x4 = reinterpret_cast<const float4*>(x);
    float4* __restrict__ o4 = reinterpret_cast<float4*>(out);

    for (int p = tid; p < n4; p += stride) {
        float4 xv = x4[p];
        float xs[4] = {xv.x, xv.y, xv.z, xv.w};
        float r[4];
        #pragma unroll
        for (int k = 0; k < 4; ++k) {
            // s = (x - a)/h = x * NGRID  (exact: power-of-2 scale)
            float s = xs[k] * (float)NGRID;
            int base = (int)floorf(s);
            // safety clamp (x in [0,1) per setup, so this is a no-op normally)
            base = min(max(base, 0), NGRID - 1);
            // replicate reference op order: t = (s + 2.0) - i
            float sp2 = s + 2.0f;
            float acc = 0.0f;
            #pragma unroll
            for (int j = 0; j < 4; ++j) {
                int ci = base + j;                 // coefficient index i-1
                float t = sp2 - (float)(ci + 1);   // i = base + 1 + j
                acc += u_basis(t) * c[ci];
            }
            r[k] = acc;
        }
        o4[p] = make_float4(r[0], r[1], r[2], r[3]);
    }
}

extern "C" void kernel_launch(void* const* d_in, const int* in_sizes, int n_in,
                              void* d_out, int out_size, void* d_ws, size_t ws_size,
                              hipStream_t stream) {
    const float* x = (const float*)d_in[0];
    const float* c = (const float*)d_in[1];
    float* out = (float*)d_out;
    int n = in_sizes[0];           // 16777216 query points
    int n4 = n / 4;                // float4 groups (n is divisible by 4)

    const int block = 256;
    const int grid = 4096;         // grid-stride: ~4 float4 iters per thread

    spline_eval_kernel<<<grid, block, 0, stream>>>(x, c, out, n4);
}

// Round 2
// 206.893 us; speedup vs baseline: 1.2484x; 1.2484x over previous
//
#include <hip/hip_runtime.h>

#define NGRID 4194304          // 2^22
#define NCOEF (NGRID + 3)
#define SEG_SHIFT 19           // 8 segments of 2^19 coefficients = 2.1 MB each
#define NSEG (NGRID >> SEG_SHIFT)

// Cubic B-spline basis, replicating the reference's op structure:
// t<=1: 4 - 6t^2 + 3t^3 ; 1<t<=2: (2-t)^3 ; else 0
__device__ __forceinline__ float u_basis(float t) {
    t = fabsf(t);
    float tt = t * t;
    float inner = 4.0f - 6.0f * tt + 3.0f * tt * t;
    float om = 2.0f - t;
    float outer = om * om * om;
    float w = (t <= 1.0f) ? inner : outer;
    return (t <= 2.0f) ? w : 0.0f;
}

__global__ __launch_bounds__(256) void spline_seg_kernel(
    const float* __restrict__ x, const float* __restrict__ c,
    float* __restrict__ out, int n4)
{
    int tid = blockIdx.x * blockDim.x + threadIdx.x;
    if (tid >= n4) return;

    const float4* __restrict__ x4 = reinterpret_cast<const float4*>(x);
    float4* __restrict__ o4 = reinterpret_cast<float4*>(out);

    float4 xv = x4[tid];
    float xs[4] = {xv.x, xv.y, xv.z, xv.w};

    int   base[4];
    float w[4][4];
    float r[4];

    // Precompute bases and all 16 basis weights (registers), identical op
    // order to the reference: s = x*n ; t = (s + 2.0) - i
    #pragma unroll
    for (int k = 0; k < 4; ++k) {
        float s = xs[k] * (float)NGRID;
        int b = (int)floorf(s);
        b = min(max(b, 0), NGRID - 1);
        base[k] = b;
        float sp2 = s + 2.0f;
        #pragma unroll
        for (int j = 0; j < 4; ++j) {
            w[k][j] = u_basis(sp2 - (float)(b + j + 1));
        }
        r[k] = 0.0f;
    }

    // Sweep table segments; all resident waves touch the same ~2.1 MB window
    // at a time -> gathers hit L2 on every XCD.
    for (int seg = 0; seg < NSEG; ++seg) {
        #pragma unroll
        for (int k = 0; k < 4; ++k) {
            if ((base[k] >> SEG_SHIFT) == seg) {
                int b = base[k];
                // same sequential accumulation order as before (j0..j3)
                float acc = w[k][0] * c[b];
                acc += w[k][1] * c[b + 1];
                acc += w[k][2] * c[b + 2];
                acc += w[k][3] * c[b + 3];
                r[k] = acc;
            }
        }
    }

    o4[tid] = make_float4(r[0], r[1], r[2], r[3]);
}

extern "C" void kernel_launch(void* const* d_in, const int* in_sizes, int n_in,
                              void* d_out, int out_size, void* d_ws, size_t ws_size,
                              hipStream_t stream) {
    const float* x = (const float*)d_in[0];
    const float* c = (const float*)d_in[1];
    float* out = (float*)d_out;
    int n = in_sizes[0];           // 16777216 query points
    int n4 = n / 4;                // one float4 per thread

    const int block = 256;
    const int grid = (n4 + block - 1) / block;   // 16384 blocks

    spline_seg_kernel<<<grid, block, 0, stream>>>(x, c, out, n4);
}